// Round 2
// baseline (1104.495 us; speedup 1.0000x reference)
//
#include <hip/hip_runtime.h>

#define BB 32
#define SS 1024
#define CINN 16

typedef float v2f __attribute__((ext_vector_type(2)));
typedef float v4f __attribute__((ext_vector_type(4)));

// ---------- accurate-for-tiny-arguments activations ----------
__device__ __forceinline__ float tanh_fast(float x) {
    float x2 = x * x;
    // |x|<=0.25: odd series, relative err < 4e-7
    float p = x * (1.f + x2 * (-0.33333334f + x2 * (0.13333333f - x2 * 0.05396825f)));
    float e = __expf(2.f * x);
    float q = 1.f - 2.f * __builtin_amdgcn_rcpf(1.f + e);
    return (fabsf(x) > 0.25f) ? q : p;
}
__device__ __forceinline__ float sig_fast(float x) {
    return 0.5f + 0.5f * tanh_fast(0.5f * x);
}

// ---------- kernel 1: fused 3x dsconv + U_i projection -> ri (B,S,16) ----------
__global__ __launch_bounds__(256) void conv_ri_kernel(
    const float* __restrict__ x,
    const float* __restrict__ w1d, const float* __restrict__ b1d,
    const float* __restrict__ w1p, const float* __restrict__ b1p,
    const float* __restrict__ w2d, const float* __restrict__ b2d,
    const float* __restrict__ w2p, const float* __restrict__ b2p,
    const float* __restrict__ w3d, const float* __restrict__ b3d,
    const float* __restrict__ w3p, const float* __restrict__ b3p,
    const float* __restrict__ Ui,
    float* __restrict__ ri)
{
    const int b = blockIdx.x >> 4;
    const int tile = blockIdx.x & 15;
    const int base = tile * 64;
    const int t = threadIdx.x;

    __shared__ float lds[12576];
    float* xs  = lds;          // [70][16]  @0
    float* y1s = lds + 1120;   // [68][16]
    float* z1s = lds + 2208;   // [68][32]
    float* y2s = lds;          // [66][32]  (overlays xs/y1s, dead)
    float* z2s = lds + 4384;   // [66][64]
    float* y3s = lds;          // [64][64]  (overlays y2s, dead)
    float* z3s = lds + 4384;   // [64][128] (overlays z2s, dead)

    for (int idx = t; idx < 70 * 16; idx += 256) {
        int p = idx >> 4, c = idx & 15;
        int s = base - 3 + p;
        xs[idx] = (s >= 0 && s < SS) ? x[((size_t)b * SS + s) * CINN + c] : 0.f;
    }
    __syncthreads();
    for (int idx = t; idx < 68 * 16; idx += 256) {
        int p = idx >> 4, c = idx & 15;
        float acc = b1d[c];
#pragma unroll
        for (int k = 0; k < 3; ++k) acc += xs[(p + k) * 16 + c] * w1d[c * 3 + k];
        y1s[idx] = acc;
    }
    __syncthreads();
    for (int idx = t; idx < 68 * 32; idx += 256) {
        int p = idx >> 5, o = idx & 31;
        int pos = base - 2 + p;
        float acc = b1p[o];
#pragma unroll
        for (int c = 0; c < 16; ++c) acc += y1s[p * 16 + c] * w1p[o * 16 + c];
        z1s[idx] = (pos >= 0 && pos < SS) ? acc : 0.f;
    }
    __syncthreads();
    for (int idx = t; idx < 66 * 32; idx += 256) {
        int p = idx >> 5, c = idx & 31;
        float acc = b2d[c];
#pragma unroll
        for (int k = 0; k < 3; ++k) acc += z1s[(p + k) * 32 + c] * w2d[c * 3 + k];
        y2s[idx] = acc;
    }
    __syncthreads();
    for (int idx = t; idx < 66 * 64; idx += 256) {
        int p = idx >> 6, o = idx & 63;
        int pos = base - 1 + p;
        float acc = b2p[o];
        for (int c = 0; c < 32; ++c) acc += y2s[p * 32 + c] * w2p[o * 32 + c];
        z2s[idx] = (pos >= 0 && pos < SS) ? acc : 0.f;
    }
    __syncthreads();
    for (int idx = t; idx < 64 * 64; idx += 256) {
        int p = idx >> 6, c = idx & 63;
        float acc = b3d[c];
#pragma unroll
        for (int k = 0; k < 3; ++k) acc += z2s[(p + k) * 64 + c] * w3d[c * 3 + k];
        y3s[idx] = acc;
    }
    __syncthreads();
    for (int idx = t; idx < 64 * 128; idx += 256) {
        int p = idx >> 7, o = idx & 127;
        float acc = b3p[o];
        for (int c = 0; c < 64; ++c) acc += y3s[p * 64 + c] * w3p[o * 64 + c];
        z3s[idx] = acc;
    }
    __syncthreads();
    for (int idx = t; idx < 64 * 16; idx += 256) {
        int p = idx >> 4, j = idx & 15;
        float acc = 0.f;
        for (int o = 0; o < 128; ++o) acc += z3s[p * 128 + o] * Ui[o * 16 + j];
        ri[((size_t)b * SS + base + p) * 16 + j] = acc;
    }
}

// ---------- kernel 2: low-rank LSTM scan, 1 block/batch, 128 threads ----------
// One barrier per step; wave-redundant r-reduction; pk_fma everywhere.
__global__ __launch_bounds__(128, 1) void lstm_scan_kernel(
    const float* __restrict__ ri,
    const float* __restrict__ Uh,
    const float* __restrict__ Vi,
    const float* __restrict__ Vh,
    const float* __restrict__ bias_i,
    const float* __restrict__ bias_h,
    float* __restrict__ hs)
{
    const int b = blockIdx.x;
    const int t = threadIdx.x;       // cell e = t
    const int wl = t & 63;           // lane within wave
    const int wv = t >> 6;           // wave id
    const int gg = wl >> 4;          // group 0..3 -> cells [32gg, 32gg+32)
    const int j  = wl & 15;          // this lane's j for the partial

    extern __shared__ float smem[];
    float* rlds = smem;                       // [1024][16] = 16384 floats
    float* hrow = smem + 16384;               // [2][160] padded h rows
    float* Pw   = smem + 16384 + 320;         // [2 waves][64] partials

    // one-time register preloads
    v2f Uv[16];
#pragma unroll
    for (int i = 0; i < 16; ++i)
        Uv[i] = v2f{ Uh[(32 * gg + 2 * i) * 16 + j], Uh[(32 * gg + 2 * i + 1) * 16 + j] };

    v2f VI2[4][8], VH2[4][8];
    float bsum[4];
#pragma unroll
    for (int k = 0; k < 4; ++k) {
#pragma unroll
        for (int jj = 0; jj < 8; ++jj) {
            VI2[k][jj] = v2f{ Vi[(2 * jj) * 512 + k * 128 + t], Vi[(2 * jj + 1) * 512 + k * 128 + t] };
            VH2[k][jj] = v2f{ Vh[(2 * jj) * 512 + k * 128 + t], Vh[(2 * jj + 1) * 512 + k * 128 + t] };
        }
        bsum[k] = bias_i[k * 128 + t] + bias_h[k * 128 + t];
    }

    { // preload ri for this batch (64 KB)
        const v4f* rg = (const v4f*)(ri + (size_t)b * (SS * 16));
        v4f* r4 = (v4f*)rlds;
        for (int i = t; i < 4096; i += 128) r4[i] = rg[i];
    }

    const int mycol = 40 * (t >> 5) + (t & 31);  // padded column for cell t
    const int gbase = 40 * gg;                   // group read base (bank-staggered)
    hrow[0 * 160 + mycol] = 0.f;                 // h_{-1} = 0 lives in row 0

    float c = 0.f;
    float dumpbuf[2][16];
    float* hsb = hs + (size_t)b * (SS * 128) + t;

    for (int s16 = 0; s16 < 64; ++s16) {
        const int cur = s16 & 1;
#pragma unroll
        for (int m = 0; m < 16; ++m) {
            const int s = s16 * 16 + m;
            const int rdrow = s & 1;             // row holding h_{s-1}

            __syncthreads();                     // h_{s-1} visible to both waves

            if (m == 0 && s16 > 0) {             // dump previous 16-step block
                float* dst = hsb + (size_t)(s16 - 1) * 16 * 128;
#pragma unroll
                for (int q = 0; q < 16; ++q) dst[q * 128] = dumpbuf[cur ^ 1][q];
            }

            // rv for this step (broadcast reads, off critical path)
            const v4f* rvp = (const v4f*)(rlds + s * 16);
            v4f R0 = rvp[0], R1 = rvp[1], R2 = rvp[2], R3 = rvp[3];

            // C: partial_j over this group's 32 cells
            const v4f* hp = (const v4f*)(hrow + rdrow * 160 + gbase);
            v2f acc = {0.f, 0.f};
#pragma unroll
            for (int cch = 0; cch < 8; ++cch) {
                v4f hv = hp[cch];
                v2f h01 = {hv.x, hv.y}, h23 = {hv.z, hv.w};
                acc += h01 * Uv[2 * cch] + h23 * Uv[2 * cch + 1];
            }
            Pw[wv * 64 + wl] = acc.x + acc.y;    // [g][j]

            // wave-private visibility fence (no barrier needed)
            asm volatile("s_waitcnt lgkmcnt(0)" ::: "memory");

            // E: rh[j] for all 16 j = sum of 4 group partials (broadcast reads)
            const v4f* pp = (const v4f*)(Pw + wv * 64);
            v4f rhA = (pp[0] + pp[4]) + (pp[8]  + pp[12]);
            v4f rhB = (pp[1] + pp[5]) + (pp[9]  + pp[13]);
            v4f rhC = (pp[2] + pp[6]) + (pp[10] + pp[14]);
            v4f rhD = (pp[3] + pp[7]) + (pp[11] + pp[15]);

            v2f rv2[8] = {{R0.x,R0.y},{R0.z,R0.w},{R1.x,R1.y},{R1.z,R1.w},
                          {R2.x,R2.y},{R2.z,R2.w},{R3.x,R3.y},{R3.z,R3.w}};
            v2f rh2[8] = {{rhA.x,rhA.y},{rhA.z,rhA.w},{rhB.x,rhB.y},{rhB.z,rhB.w},
                          {rhC.x,rhC.y},{rhC.z,rhC.w},{rhD.x,rhD.y},{rhD.z,rhD.w}};

            // F: gates (pk_fma)
            v2f a0 = {0.f,0.f}, a1 = {0.f,0.f}, a2 = {0.f,0.f}, a3 = {0.f,0.f};
#pragma unroll
            for (int jj = 0; jj < 8; ++jj) {
                a0 += rv2[jj] * VI2[0][jj] + rh2[jj] * VH2[0][jj];
                a1 += rv2[jj] * VI2[1][jj] + rh2[jj] * VH2[1][jj];
                a2 += rv2[jj] * VI2[2][jj] + rh2[jj] * VH2[2][jj];
                a3 += rv2[jj] * VI2[3][jj] + rh2[jj] * VH2[3][jj];
            }
            float g0 = bsum[0] + a0.x + a0.y;
            float g1 = bsum[1] + a1.x + a1.y;
            float g2 = bsum[2] + a2.x + a2.y;
            float g3 = bsum[3] + a3.x + a3.y;

            float si = sig_fast(g0);
            float sf = sig_fast(g1);
            float tc = tanh_fast(g2);
            float so = sig_fast(g3);
            c = sf * c + si * tc;
            float hn = so * tanh_fast(c);

            dumpbuf[cur][m] = hn;
            hrow[(rdrow ^ 1) * 160 + mycol] = hn;  // h_s -> other row
        }
    }
    { // final block dump
        float* dst = hsb + (size_t)63 * 16 * 128;
#pragma unroll
        for (int q = 0; q < 16; ++q) dst[q * 128] = dumpbuf[1][q];
    }
}

// ---------- kernel 3: last-query attention + head, 1 block/batch ----------
__global__ __launch_bounds__(256) void attn_head_kernel(
    const float* __restrict__ hs,
    const float* __restrict__ Wq, const float* __restrict__ bq,
    const float* __restrict__ Wk,
    const float* __restrict__ Wv, const float* __restrict__ bv,
    const float* __restrict__ Wo, const float* __restrict__ bo,
    const float* __restrict__ Wfc, const float* __restrict__ bfc,
    float* __restrict__ out)
{
    const int b = blockIdx.x;
    const int t = threadIdx.x;
    const float* hb = hs + (size_t)b * (SS * 128);

    __shared__ float hlast[128];
    __shared__ float qv[128];
    __shared__ float wqt[2][128];
    __shared__ float sc[2][1024];
    __shared__ float red[8];
    __shared__ float hbarw[2][128];
    __shared__ float att[128];
    __shared__ float yv[128];

    if (t < 128) hlast[t] = hb[(size_t)1023 * 128 + t];
    __syncthreads();
    if (t < 128) {
        float acc = bq[t];
        for (int c = 0; c < 128; ++c) acc += hlast[c] * Wq[c * 128 + t];
        qv[t] = acc;
    }
    __syncthreads();
    {
        int h = t >> 7, c0 = t & 127;
        float acc = 0.f;
        for (int d = 0; d < 64; ++d) acc += Wk[c0 * 128 + h * 64 + d] * qv[h * 64 + d];
        wqt[h][c0] = acc;
    }
    __syncthreads();
    for (int rr = 0; rr < 4; ++rr) {
        int row = (rr << 8) + t;
        const float4* hp = (const float4*)(hb + (size_t)row * 128);
        float a0 = 0.f, a1 = 0.f;
#pragma unroll 8
        for (int cq = 0; cq < 32; ++cq) {
            float4 hv = hp[cq];
            int cb = cq * 4;
            a0 += hv.x * wqt[0][cb] + hv.y * wqt[0][cb + 1] + hv.z * wqt[0][cb + 2] + hv.w * wqt[0][cb + 3];
            a1 += hv.x * wqt[1][cb] + hv.y * wqt[1][cb + 1] + hv.z * wqt[1][cb + 2] + hv.w * wqt[1][cb + 3];
        }
        sc[0][row] = a0 * 0.125f;
        sc[1][row] = a1 * 0.125f;
    }
    __syncthreads();
    for (int h = 0; h < 2; ++h) {
        float lm = -3.4e38f;
        for (int i = t; i < 1024; i += 256) lm = fmaxf(lm, sc[h][i]);
        for (int off = 1; off < 64; off <<= 1) lm = fmaxf(lm, __shfl_xor(lm, off, 64));
        if ((t & 63) == 0) red[t >> 6] = lm;
        __syncthreads();
        float m = fmaxf(fmaxf(red[0], red[1]), fmaxf(red[2], red[3]));
        float ls = 0.f;
        for (int i = t; i < 1024; i += 256) {
            float e = __expf(sc[h][i] - m);
            sc[h][i] = e;
            ls += e;
        }
        for (int off = 1; off < 64; off <<= 1) ls += __shfl_xor(ls, off, 64);
        if ((t & 63) == 0) red[4 + (t >> 6)] = ls;
        __syncthreads();
        float invL = __builtin_amdgcn_rcpf((red[4] + red[5]) + (red[6] + red[7]));
        for (int i = t; i < 1024; i += 256) sc[h][i] *= invL;
        __syncthreads();
    }
    {
        int h = t >> 7, c0 = t & 127;
        float a0 = 0.f, a1 = 0.f, a2 = 0.f, a3 = 0.f;
        for (int row = 0; row < 1024; row += 4) {
            a0 += sc[h][row]     * hb[(size_t)(row)     * 128 + c0];
            a1 += sc[h][row + 1] * hb[(size_t)(row + 1) * 128 + c0];
            a2 += sc[h][row + 2] * hb[(size_t)(row + 2) * 128 + c0];
            a3 += sc[h][row + 3] * hb[(size_t)(row + 3) * 128 + c0];
        }
        hbarw[h][c0] = (a0 + a1) + (a2 + a3);
    }
    __syncthreads();
    if (t < 128) {
        int h = t >> 6;
        float acc = bv[t];
        for (int c = 0; c < 128; ++c) acc += hbarw[h][c] * Wv[c * 128 + t];
        att[t] = acc;
    }
    __syncthreads();
    if (t < 128) {
        float acc = bo[t];
        for (int c = 0; c < 128; ++c) acc += att[c] * Wo[c * 128 + t];
        yv[t] = acc;
    }
    __syncthreads();
    if (t < 18) {
        float acc = bfc[t];
        for (int c = 0; c < 128; ++c) acc += yv[c] * Wfc[c * 18 + t];
        out[b * 18 + t] = acc;
    }
}

extern "C" void kernel_launch(void* const* d_in, const int* in_sizes, int n_in,
                              void* d_out, int out_size, void* d_ws, size_t ws_size,
                              hipStream_t stream) {
    const float* x    = (const float*)d_in[0];
    const float* w1d  = (const float*)d_in[1];
    const float* b1d  = (const float*)d_in[2];
    const float* w1p  = (const float*)d_in[3];
    const float* b1p  = (const float*)d_in[4];
    const float* w2d  = (const float*)d_in[5];
    const float* b2d  = (const float*)d_in[6];
    const float* w2p  = (const float*)d_in[7];
    const float* b2p  = (const float*)d_in[8];
    const float* w3d  = (const float*)d_in[9];
    const float* b3d  = (const float*)d_in[10];
    const float* w3p  = (const float*)d_in[11];
    const float* b3p  = (const float*)d_in[12];
    const float* Ui   = (const float*)d_in[13];
    const float* Vi   = (const float*)d_in[14];
    const float* Uh   = (const float*)d_in[15];
    const float* Vh   = (const float*)d_in[16];
    const float* bi   = (const float*)d_in[17];
    const float* bh   = (const float*)d_in[18];
    const float* Wq   = (const float*)d_in[19];
    const float* bq   = (const float*)d_in[20];
    const float* Wk   = (const float*)d_in[21];
    // d_in[22] = bk: cancels in softmax (constant shift per (b,h))
    const float* Wv   = (const float*)d_in[23];
    const float* bv   = (const float*)d_in[24];
    const float* Wo   = (const float*)d_in[25];
    const float* bo   = (const float*)d_in[26];
    const float* Wfc  = (const float*)d_in[27];
    const float* bfc  = (const float*)d_in[28];

    float* ri = (float*)d_ws;                       // B*S*16 floats (2 MB)
    float* hs = ri + (size_t)BB * SS * 16;          // B*S*128 floats (16 MB)

    conv_ri_kernel<<<dim3(512), dim3(256), 0, stream>>>(
        x, w1d, b1d, w1p, b1p, w2d, b2d, w2p, b2p, w3d, b3d, w3p, b3p, Ui, ri);
    // dynamic LDS: 16384 (rlds) + 320 (hrow) + 128 (Pw) floats = 67328 B
    lstm_scan_kernel<<<dim3(32), dim3(128), 67328, stream>>>(
        ri, Uh, Vi, Vh, bi, bh, hs);
    attn_head_kernel<<<dim3(32), dim3(256), 0, stream>>>(
        hs, Wq, bq, Wk, Wv, bv, Wo, bo, Wfc, bfc, (float*)d_out);
}

// Round 3
// 657.280 us; speedup vs baseline: 1.6804x; 1.6804x over previous
//
#include <hip/hip_runtime.h>

#define BB 32
#define SS 1024
#define CINN 16

typedef float v2f __attribute__((ext_vector_type(2)));
typedef float v4f __attribute__((ext_vector_type(4)));

// ---------- accurate-for-tiny-arguments activations ----------
__device__ __forceinline__ float tanh_fast(float x) {
    float x2 = x * x;
    float p = x * (1.f + x2 * (-0.33333334f + x2 * (0.13333333f - x2 * 0.05396825f)));
    float e = __expf(2.f * x);
    float q = 1.f - 2.f * __builtin_amdgcn_rcpf(1.f + e);
    return (fabsf(x) > 0.25f) ? q : p;
}
__device__ __forceinline__ float sig_fast(float x) {
    return 0.5f + 0.5f * tanh_fast(0.5f * x);
}

// ---------- kernel 1: fused 3x dsconv + U_i projection -> ri (B,S,16) ----------
__global__ __launch_bounds__(256) void conv_ri_kernel(
    const float* __restrict__ x,
    const float* __restrict__ w1d, const float* __restrict__ b1d,
    const float* __restrict__ w1p, const float* __restrict__ b1p,
    const float* __restrict__ w2d, const float* __restrict__ b2d,
    const float* __restrict__ w2p, const float* __restrict__ b2p,
    const float* __restrict__ w3d, const float* __restrict__ b3d,
    const float* __restrict__ w3p, const float* __restrict__ b3p,
    const float* __restrict__ Ui,
    float* __restrict__ ri)
{
    const int b = blockIdx.x >> 4;
    const int tile = blockIdx.x & 15;
    const int base = tile * 64;
    const int t = threadIdx.x;

    __shared__ float lds[12576];
    float* xs  = lds;          // [70][16]
    float* y1s = lds + 1120;   // [68][16]
    float* z1s = lds + 2208;   // [68][32]
    float* y2s = lds;          // [66][32]
    float* z2s = lds + 4384;   // [66][64]
    float* y3s = lds;          // [64][64]
    float* z3s = lds + 4384;   // [64][128]

    for (int idx = t; idx < 70 * 16; idx += 256) {
        int p = idx >> 4, c = idx & 15;
        int s = base - 3 + p;
        xs[idx] = (s >= 0 && s < SS) ? x[((size_t)b * SS + s) * CINN + c] : 0.f;
    }
    __syncthreads();
    for (int idx = t; idx < 68 * 16; idx += 256) {
        int p = idx >> 4, c = idx & 15;
        float acc = b1d[c];
#pragma unroll
        for (int k = 0; k < 3; ++k) acc += xs[(p + k) * 16 + c] * w1d[c * 3 + k];
        y1s[idx] = acc;
    }
    __syncthreads();
    for (int idx = t; idx < 68 * 32; idx += 256) {
        int p = idx >> 5, o = idx & 31;
        int pos = base - 2 + p;
        float acc = b1p[o];
#pragma unroll
        for (int c = 0; c < 16; ++c) acc += y1s[p * 16 + c] * w1p[o * 16 + c];
        z1s[idx] = (pos >= 0 && pos < SS) ? acc : 0.f;
    }
    __syncthreads();
    for (int idx = t; idx < 66 * 32; idx += 256) {
        int p = idx >> 5, c = idx & 31;
        float acc = b2d[c];
#pragma unroll
        for (int k = 0; k < 3; ++k) acc += z1s[(p + k) * 32 + c] * w2d[c * 3 + k];
        y2s[idx] = acc;
    }
    __syncthreads();
    for (int idx = t; idx < 66 * 64; idx += 256) {
        int p = idx >> 6, o = idx & 63;
        int pos = base - 1 + p;
        float acc = b2p[o];
        for (int c = 0; c < 32; ++c) acc += y2s[p * 32 + c] * w2p[o * 32 + c];
        z2s[idx] = (pos >= 0 && pos < SS) ? acc : 0.f;
    }
    __syncthreads();
    for (int idx = t; idx < 64 * 64; idx += 256) {
        int p = idx >> 6, c = idx & 63;
        float acc = b3d[c];
#pragma unroll
        for (int k = 0; k < 3; ++k) acc += z2s[(p + k) * 64 + c] * w3d[c * 3 + k];
        y3s[idx] = acc;
    }
    __syncthreads();
    for (int idx = t; idx < 64 * 128; idx += 256) {
        int p = idx >> 7, o = idx & 127;
        float acc = b3p[o];
        for (int c = 0; c < 64; ++c) acc += y3s[p * 64 + c] * w3p[o * 64 + c];
        z3s[idx] = acc;
    }
    __syncthreads();
    for (int idx = t; idx < 64 * 16; idx += 256) {
        int p = idx >> 4, j = idx & 15;
        float acc = 0.f;
        for (int o = 0; o < 128; ++o) acc += z3s[p * 128 + o] * Ui[o * 16 + j];
        ri[((size_t)b * SS + base + p) * 16 + j] = acc;
    }
}

// ---------- kernel 2: low-rank LSTM scan ----------
// 2 waves/batch; wave-local h (LDS row per wave, wave-ordered, no barrier);
// one raw s_barrier/step for the 16-float r exchange (parity double-buffered);
// V/U/bias pinned in VGPRs via opaque asm; h stored to global every step
// (raw barrier never drains vmcnt -> stores fully backgrounded).
__global__ __launch_bounds__(128, 1) void lstm_scan_kernel(
    const float* __restrict__ ri,
    const float* __restrict__ Uh,
    const float* __restrict__ Vi,
    const float* __restrict__ Vh,
    const float* __restrict__ bias_i,
    const float* __restrict__ bias_h,
    float* __restrict__ hs)
{
    const int b = blockIdx.x;
    const int t = threadIdx.x;       // cell e = t
    const int l = t & 63;            // lane
    const int wv = t >> 6;           // wave id
    const int grp = l >> 4;          // 4 groups of 16 lanes per wave
    const int j = l & 15;            // this lane's j for the r-partial

    extern __shared__ float smem[];
    float* rlds = smem;              // [1024][16]
    float* hrow = smem + 16384;      // [128] h (wave w owns [64w,64w+64))
    float* rws  = smem + 16384 + 128;// [2 parity][2 wave][16]

    // ---- one-time register preloads (then pinned) ----
    // partial_j covers cells [64*wv + 16*grp, +16)
    const int cellbase = 64 * wv + 16 * grp;
    v2f Uv2[8];
#pragma unroll
    for (int i = 0; i < 8; ++i)
        Uv2[i] = v2f{ Uh[(cellbase + 2 * i) * 16 + j], Uh[(cellbase + 2 * i + 1) * 16 + j] };

    v2f VI2[4][8], VH2[4][8];
    float bsum[4];
#pragma unroll
    for (int k = 0; k < 4; ++k) {
#pragma unroll
        for (int jj = 0; jj < 8; ++jj) {
            VI2[k][jj] = v2f{ Vi[(2 * jj) * 512 + k * 128 + t], Vi[(2 * jj + 1) * 512 + k * 128 + t] };
            VH2[k][jj] = v2f{ Vh[(2 * jj) * 512 + k * 128 + t], Vh[(2 * jj + 1) * 512 + k * 128 + t] };
        }
        bsum[k] = bias_i[k * 128 + t] + bias_h[k * 128 + t];
    }
    // pin: stop the compiler from sinking/rematerializing these per step
#pragma unroll
    for (int k = 0; k < 4; ++k) {
#pragma unroll
        for (int jj = 0; jj < 8; ++jj)
            asm volatile("" : "+v"(VI2[k][jj]), "+v"(VH2[k][jj]));
        asm volatile("" : "+v"(bsum[k]));
    }
#pragma unroll
    for (int i = 0; i < 8; ++i) asm volatile("" : "+v"(Uv2[i]));

    { // preload ri for this batch (64 KB)
        const v4f* rg = (const v4f*)(ri + (size_t)b * (SS * 16));
        v4f* r4 = (v4f*)rlds;
        for (int i = t; i < 4096; i += 128) r4[i] = rg[i];
    }
    hrow[t] = 0.f;                   // own-wave h_{-1}=0 (wave-ordered)
    float c = 0.f;
    float* hsb = hs + (size_t)b * (SS * 128) + t;
    __syncthreads();                 // rlds ready (cross-wave)

    for (int s = 0; s < SS; ++s) {
        const int par = s & 1;

        // rv for this step (broadcast LDS reads, off critical path)
        const v4f* rvp = (const v4f*)(rlds + s * 16);
        v4f R0 = rvp[0], R1 = rvp[1], R2 = rvp[2], R3 = rvp[3];

        // partial_j over own group's 16 cells (own-wave LDS, no barrier)
        const v4f* hp = (const v4f*)(hrow + cellbase);
        v4f h0 = hp[0], h1 = hp[1], h2 = hp[2], h3 = hp[3];
        v2f pacc = v2f{h0.x, h0.y} * Uv2[0] + v2f{h0.z, h0.w} * Uv2[1]
                 + v2f{h1.x, h1.y} * Uv2[2] + v2f{h1.z, h1.w} * Uv2[3]
                 + v2f{h2.x, h2.y} * Uv2[4] + v2f{h2.z, h2.w} * Uv2[5]
                 + v2f{h3.x, h3.y} * Uv2[6] + v2f{h3.z, h3.w} * Uv2[7];
        float p = pacc.x + pacc.y;
        p += __shfl_xor(p, 16, 64);  // sum 4 groups -> wave-total r_j
        p += __shfl_xor(p, 32, 64);
        if (l < 16) rws[par * 32 + wv * 16 + l] = p;

        // rv-half of the gates while the write drains / other wave catches up
        v2f rv2[8] = {{R0.x,R0.y},{R0.z,R0.w},{R1.x,R1.y},{R1.z,R1.w},
                      {R2.x,R2.y},{R2.z,R2.w},{R3.x,R3.y},{R3.z,R3.w}};
        v2f a0 = {0.f,0.f}, a1 = {0.f,0.f}, a2 = {0.f,0.f}, a3 = {0.f,0.f};
#pragma unroll
        for (int jj = 0; jj < 8; ++jj) {
            a0 += rv2[jj] * VI2[0][jj];
            a1 += rv2[jj] * VI2[1][jj];
            a2 += rv2[jj] * VI2[2][jj];
            a3 += rv2[jj] * VI2[3][jj];
        }

        asm volatile("s_waitcnt lgkmcnt(0)" ::: "memory");
        __builtin_amdgcn_s_barrier();
        __builtin_amdgcn_sched_barrier(0);

        // rh = wave0 partial + wave1 partial (broadcast reads)
        const v4f* pp = (const v4f*)(rws + par * 32);
        v4f q0 = pp[0], q1 = pp[1], q2 = pp[2], q3 = pp[3];
        v4f q4 = pp[4], q5 = pp[5], q6 = pp[6], q7 = pp[7];
        v4f r0 = q0 + q4, r1 = q1 + q5, r2 = q2 + q6, r3 = q3 + q7;
        v2f rh2[8] = {{r0.x,r0.y},{r0.z,r0.w},{r1.x,r1.y},{r1.z,r1.w},
                      {r2.x,r2.y},{r2.z,r2.w},{r3.x,r3.y},{r3.z,r3.w}};
#pragma unroll
        for (int jj = 0; jj < 8; ++jj) {
            a0 += rh2[jj] * VH2[0][jj];
            a1 += rh2[jj] * VH2[1][jj];
            a2 += rh2[jj] * VH2[2][jj];
            a3 += rh2[jj] * VH2[3][jj];
        }
        float g0 = bsum[0] + a0.x + a0.y;
        float g1 = bsum[1] + a1.x + a1.y;
        float g2 = bsum[2] + a2.x + a2.y;
        float g3 = bsum[3] + a3.x + a3.y;

        float si = sig_fast(g0);
        float sf = sig_fast(g1);
        float tc = tanh_fast(g2);
        float so = sig_fast(g3);
        c = sf * c + si * tc;
        float hn = so * tanh_fast(c);

        hrow[t] = hn;                // own-wave, wave-ordered vs next read
        hsb[(size_t)s * 128] = hn;   // coalesced 512B/step, never drained at barrier
    }
}

// ---------- kernel 3: last-query attention + head, 1 block/batch ----------
__global__ __launch_bounds__(256) void attn_head_kernel(
    const float* __restrict__ hs,
    const float* __restrict__ Wq, const float* __restrict__ bq,
    const float* __restrict__ Wk,
    const float* __restrict__ Wv, const float* __restrict__ bv,
    const float* __restrict__ Wo, const float* __restrict__ bo,
    const float* __restrict__ Wfc, const float* __restrict__ bfc,
    float* __restrict__ out)
{
    const int b = blockIdx.x;
    const int t = threadIdx.x;
    const float* hb = hs + (size_t)b * (SS * 128);

    __shared__ float hlast[128];
    __shared__ float qv[128];
    __shared__ float wqt[2][128];
    __shared__ float sc[2][1024];
    __shared__ float red[8];
    __shared__ float hbarw[2][128];
    __shared__ float att[128];
    __shared__ float yv[128];

    if (t < 128) hlast[t] = hb[(size_t)1023 * 128 + t];
    __syncthreads();
    if (t < 128) {
        float acc = bq[t];
        for (int c = 0; c < 128; ++c) acc += hlast[c] * Wq[c * 128 + t];
        qv[t] = acc;
    }
    __syncthreads();
    {
        int h = t >> 7, c0 = t & 127;
        float acc = 0.f;
        for (int d = 0; d < 64; ++d) acc += Wk[c0 * 128 + h * 64 + d] * qv[h * 64 + d];
        wqt[h][c0] = acc;
    }
    __syncthreads();
    for (int rr = 0; rr < 4; ++rr) {
        int row = (rr << 8) + t;
        const float4* hp = (const float4*)(hb + (size_t)row * 128);
        float a0 = 0.f, a1 = 0.f;
#pragma unroll 8
        for (int cq = 0; cq < 32; ++cq) {
            float4 hv = hp[cq];
            int cb = cq * 4;
            a0 += hv.x * wqt[0][cb] + hv.y * wqt[0][cb + 1] + hv.z * wqt[0][cb + 2] + hv.w * wqt[0][cb + 3];
            a1 += hv.x * wqt[1][cb] + hv.y * wqt[1][cb + 1] + hv.z * wqt[1][cb + 2] + hv.w * wqt[1][cb + 3];
        }
        sc[0][row] = a0 * 0.125f;
        sc[1][row] = a1 * 0.125f;
    }
    __syncthreads();
    for (int h = 0; h < 2; ++h) {
        float lm = -3.4e38f;
        for (int i = t; i < 1024; i += 256) lm = fmaxf(lm, sc[h][i]);
        for (int off = 1; off < 64; off <<= 1) lm = fmaxf(lm, __shfl_xor(lm, off, 64));
        if ((t & 63) == 0) red[t >> 6] = lm;
        __syncthreads();
        float m = fmaxf(fmaxf(red[0], red[1]), fmaxf(red[2], red[3]));
        float ls = 0.f;
        for (int i = t; i < 1024; i += 256) {
            float e = __expf(sc[h][i] - m);
            sc[h][i] = e;
            ls += e;
        }
        for (int off = 1; off < 64; off <<= 1) ls += __shfl_xor(ls, off, 64);
        if ((t & 63) == 0) red[4 + (t >> 6)] = ls;
        __syncthreads();
        float invL = __builtin_amdgcn_rcpf((red[4] + red[5]) + (red[6] + red[7]));
        for (int i = t; i < 1024; i += 256) sc[h][i] *= invL;
        __syncthreads();
    }
    {
        int h = t >> 7, c0 = t & 127;
        float a0 = 0.f, a1 = 0.f, a2 = 0.f, a3 = 0.f;
        for (int row = 0; row < 1024; row += 4) {
            a0 += sc[h][row]     * hb[(size_t)(row)     * 128 + c0];
            a1 += sc[h][row + 1] * hb[(size_t)(row + 1) * 128 + c0];
            a2 += sc[h][row + 2] * hb[(size_t)(row + 2) * 128 + c0];
            a3 += sc[h][row + 3] * hb[(size_t)(row + 3) * 128 + c0];
        }
        hbarw[h][c0] = (a0 + a1) + (a2 + a3);
    }
    __syncthreads();
    if (t < 128) {
        int h = t >> 6;
        float acc = bv[t];
        for (int c = 0; c < 128; ++c) acc += hbarw[h][c] * Wv[c * 128 + t];
        att[t] = acc;
    }
    __syncthreads();
    if (t < 128) {
        float acc = bo[t];
        for (int c = 0; c < 128; ++c) acc += att[c] * Wo[c * 128 + t];
        yv[t] = acc;
    }
    __syncthreads();
    if (t < 18) {
        float acc = bfc[t];
        for (int c = 0; c < 128; ++c) acc += yv[c] * Wfc[c * 18 + t];
        out[b * 18 + t] = acc;
    }
}

extern "C" void kernel_launch(void* const* d_in, const int* in_sizes, int n_in,
                              void* d_out, int out_size, void* d_ws, size_t ws_size,
                              hipStream_t stream) {
    const float* x    = (const float*)d_in[0];
    const float* w1d  = (const float*)d_in[1];
    const float* b1d  = (const float*)d_in[2];
    const float* w1p  = (const float*)d_in[3];
    const float* b1p  = (const float*)d_in[4];
    const float* w2d  = (const float*)d_in[5];
    const float* b2d  = (const float*)d_in[6];
    const float* w2p  = (const float*)d_in[7];
    const float* b2p  = (const float*)d_in[8];
    const float* w3d  = (const float*)d_in[9];
    const float* b3d  = (const float*)d_in[10];
    const float* w3p  = (const float*)d_in[11];
    const float* b3p  = (const float*)d_in[12];
    const float* Ui   = (const float*)d_in[13];
    const float* Vi   = (const float*)d_in[14];
    const float* Uh   = (const float*)d_in[15];
    const float* Vh   = (const float*)d_in[16];
    const float* bi   = (const float*)d_in[17];
    const float* bh   = (const float*)d_in[18];
    const float* Wq   = (const float*)d_in[19];
    const float* bq   = (const float*)d_in[20];
    const float* Wk   = (const float*)d_in[21];
    // d_in[22] = bk: cancels in softmax (constant shift per (b,h))
    const float* Wv   = (const float*)d_in[23];
    const float* bv   = (const float*)d_in[24];
    const float* Wo   = (const float*)d_in[25];
    const float* bo   = (const float*)d_in[26];
    const float* Wfc  = (const float*)d_in[27];
    const float* bfc  = (const float*)d_in[28];

    float* ri = (float*)d_ws;                       // B*S*16 floats (2 MB)
    float* hs = ri + (size_t)BB * SS * 16;          // B*S*128 floats (16 MB)

    conv_ri_kernel<<<dim3(512), dim3(256), 0, stream>>>(
        x, w1d, b1d, w1p, b1p, w2d, b2d, w2p, b2p, w3d, b3d, w3p, b3p, Ui, ri);
    // dynamic LDS: 16384 (rlds) + 128 (hrow) + 64 (rws) floats = 66304 B
    lstm_scan_kernel<<<dim3(32), dim3(128), 66304, stream>>>(
        ri, Uh, Vi, Vh, bi, bh, hs);
    attn_head_kernel<<<dim3(32), dim3(256), 0, stream>>>(
        hs, Wq, bq, Wk, Wv, bv, Wo, bo, Wfc, bfc, (float*)d_out);
}

// Round 5
// 613.861 us; speedup vs baseline: 1.7993x; 1.0707x over previous
//
#include <hip/hip_runtime.h>

#define BB 32
#define SS 1024
#define CINN 16

typedef float v2f __attribute__((ext_vector_type(2)));
typedef float v4f __attribute__((ext_vector_type(4)));
typedef __fp16 h2 __attribute__((ext_vector_type(2)));   // matches cvt_pkrtz/fdot2 builtin type

// ---------- exact-path activations (any argument) ----------
__device__ __forceinline__ float tanh_fast(float x) {
    float x2 = x * x;
    float p = x * (1.f + x2 * (-0.33333334f + x2 * (0.13333333f - x2 * 0.05396825f)));
    float e = __expf(2.f * x);
    float q = 1.f - 2.f * __builtin_amdgcn_rcpf(1.f + e);
    return (fabsf(x) > 0.25f) ? q : p;
}
__device__ __forceinline__ float sig_fast(float x) {
    return 0.5f + 0.5f * tanh_fast(0.5f * x);
}
// ---------- tiny-argument polys (|x| <= 0.07 for sig, <= 0.15 for tanh) ----------
__device__ __forceinline__ float tanh_p(float x) {
    float x2 = x * x;
    return x * (1.f + x2 * (-0.33333334f + x2 * 0.13333333f));
}
__device__ __forceinline__ float sig_p(float x) {
    float x2 = x * x;
    return 0.5f + x * (0.25f + x2 * (-0.020833334f + x2 * 0.0020833334f));
}

// ---------- kernel 1: fused 3x dsconv + (U_i*1024) projection -> ri_scaled ----------
__global__ __launch_bounds__(256) void conv_ri_kernel(
    const float* __restrict__ x,
    const float* __restrict__ w1d, const float* __restrict__ b1d,
    const float* __restrict__ w1p, const float* __restrict__ b1p,
    const float* __restrict__ w2d, const float* __restrict__ b2d,
    const float* __restrict__ w2p, const float* __restrict__ b2p,
    const float* __restrict__ w3d, const float* __restrict__ b3d,
    const float* __restrict__ w3p, const float* __restrict__ b3p,
    const float* __restrict__ Ui,
    float* __restrict__ ri)
{
    const int b = blockIdx.x >> 4;
    const int tile = blockIdx.x & 15;
    const int base = tile * 64;
    const int t = threadIdx.x;

    __shared__ float lds[12576];
    float* xs  = lds;          // [70][16]
    float* y1s = lds + 1120;   // [68][16]
    float* z1s = lds + 2208;   // [68][32]
    float* y2s = lds;          // [66][32]
    float* z2s = lds + 4384;   // [66][64]
    float* y3s = lds;          // [64][64]
    float* z3s = lds + 4384;   // [64][128]

    for (int idx = t; idx < 70 * 16; idx += 256) {
        int p = idx >> 4, c = idx & 15;
        int s = base - 3 + p;
        xs[idx] = (s >= 0 && s < SS) ? x[((size_t)b * SS + s) * CINN + c] : 0.f;
    }
    __syncthreads();
    for (int idx = t; idx < 68 * 16; idx += 256) {
        int p = idx >> 4, c = idx & 15;
        float acc = b1d[c];
#pragma unroll
        for (int k = 0; k < 3; ++k) acc += xs[(p + k) * 16 + c] * w1d[c * 3 + k];
        y1s[idx] = acc;
    }
    __syncthreads();
    for (int idx = t; idx < 68 * 32; idx += 256) {
        int p = idx >> 5, o = idx & 31;
        int pos = base - 2 + p;
        float acc = b1p[o];
#pragma unroll
        for (int c = 0; c < 16; ++c) acc += y1s[p * 16 + c] * w1p[o * 16 + c];
        z1s[idx] = (pos >= 0 && pos < SS) ? acc : 0.f;
    }
    __syncthreads();
    for (int idx = t; idx < 66 * 32; idx += 256) {
        int p = idx >> 5, c = idx & 31;
        float acc = b2d[c];
#pragma unroll
        for (int k = 0; k < 3; ++k) acc += z1s[(p + k) * 32 + c] * w2d[c * 3 + k];
        y2s[idx] = acc;
    }
    __syncthreads();
    for (int idx = t; idx < 66 * 64; idx += 256) {
        int p = idx >> 6, o = idx & 63;
        int pos = base - 1 + p;
        float acc = b2p[o];
        for (int c = 0; c < 32; ++c) acc += y2s[p * 32 + c] * w2p[o * 32 + c];
        z2s[idx] = (pos >= 0 && pos < SS) ? acc : 0.f;
    }
    __syncthreads();
    for (int idx = t; idx < 64 * 64; idx += 256) {
        int p = idx >> 6, c = idx & 63;
        float acc = b3d[c];
#pragma unroll
        for (int k = 0; k < 3; ++k) acc += z2s[(p + k) * 64 + c] * w3d[c * 3 + k];
        y3s[idx] = acc;
    }
    __syncthreads();
    for (int idx = t; idx < 64 * 128; idx += 256) {
        int p = idx >> 7, o = idx & 127;
        float acc = b3p[o];
        for (int c = 0; c < 64; ++c) acc += y3s[p * 64 + c] * w3p[o * 64 + c];
        z3s[idx] = acc;
    }
    __syncthreads();
    for (int idx = t; idx < 64 * 16; idx += 256) {
        int p = idx >> 4, j = idx & 15;
        float acc = 0.f;
        for (int o = 0; o < 128; ++o) acc += z3s[p * 128 + o] * Ui[o * 16 + j];
        // x1024: keeps rv in f16-normal range for the fdot2 gate path in the scan
        ri[((size_t)b * SS + base + p) * 16 + j] = acc * 1024.f;
    }
}

// ---------- kernel 2: low-rank LSTM scan ----------
// 2 waves/batch; wave-local h; one raw s_barrier/step for the 16-float r
// exchange; V_i/V_h packed f16 in VGPRs (fdot2), x1024 pre-scaling; poly
// activations with wave-uniform exact-path escape.
__global__ __launch_bounds__(128, 1) void lstm_scan_kernel(
    const float* __restrict__ ri,
    const float* __restrict__ Uh,
    const float* __restrict__ Vi,
    const float* __restrict__ Vh,
    const float* __restrict__ bias_i,
    const float* __restrict__ bias_h,
    float* __restrict__ hs)
{
    const int b = blockIdx.x;
    const int t = threadIdx.x;       // cell e = t
    const int l = t & 63;            // lane
    const int wv = t >> 6;           // wave id
    const int grp = l >> 4;          // 4 groups of 16 lanes per wave
    const int j = l & 15;            // this lane's j for the r-partial

    extern __shared__ float smem[];
    float* rlds = smem;              // [1024][16] scaled ri
    float* hrow = smem + 16384;      // [128] h (wave w owns [64w,64w+64))
    float* rws  = smem + 16384 + 128;// [2 parity][2 wave][16]

    // ---- one-time register preloads ----
    const int cellbase = 64 * wv + 16 * grp;
    v2f Uv2[8];                      // Uh rows x1024 (scales rh into f16 range)
#pragma unroll
    for (int i = 0; i < 8; ++i)
        Uv2[i] = v2f{ Uh[(cellbase + 2 * i) * 16 + j] * 1024.f,
                      Uh[(cellbase + 2 * i + 1) * 16 + j] * 1024.f };

    h2 VIh[4][8], VHh[4][8];         // packed f16: 64 VGPRs total
    float bsum[4];
#pragma unroll
    for (int k = 0; k < 4; ++k) {
#pragma unroll
        for (int jj = 0; jj < 8; ++jj) {
            VIh[k][jj] = __builtin_amdgcn_cvt_pkrtz(Vi[(2 * jj) * 512 + k * 128 + t],
                                                    Vi[(2 * jj + 1) * 512 + k * 128 + t]);
            VHh[k][jj] = __builtin_amdgcn_cvt_pkrtz(Vh[(2 * jj) * 512 + k * 128 + t],
                                                    Vh[(2 * jj + 1) * 512 + k * 128 + t]);
        }
        bsum[k] = bias_i[k * 128 + t] + bias_h[k * 128 + t];
    }
    // pin the packed weights so they stay register-resident
#pragma unroll
    for (int k = 0; k < 4; ++k) {
#pragma unroll
        for (int jj = 0; jj < 8; ++jj)
            asm volatile("" : "+v"(VIh[k][jj]), "+v"(VHh[k][jj]));
        asm volatile("" : "+v"(bsum[k]));
    }
#pragma unroll
    for (int i = 0; i < 8; ++i) asm volatile("" : "+v"(Uv2[i]));

    { // preload scaled ri for this batch (64 KB)
        const v4f* rg = (const v4f*)(ri + (size_t)b * (SS * 16));
        v4f* r4 = (v4f*)rlds;
        for (int i = t; i < 4096; i += 128) r4[i] = rg[i];
    }
    hrow[t] = 0.f;
    float c = 0.f;
    float* hsb = hs + (size_t)b * (SS * 128) + t;
    __syncthreads();

    for (int s = 0; s < SS; ++s) {
        const int par = s & 1;

        // rv (scaled) for this step: broadcast LDS reads + f16 pack (off path)
        const v4f* rvp = (const v4f*)(rlds + s * 16);
        v4f R0 = rvp[0], R1 = rvp[1], R2 = rvp[2], R3 = rvp[3];
        h2 rvh[8];
        rvh[0] = __builtin_amdgcn_cvt_pkrtz(R0.x, R0.y);
        rvh[1] = __builtin_amdgcn_cvt_pkrtz(R0.z, R0.w);
        rvh[2] = __builtin_amdgcn_cvt_pkrtz(R1.x, R1.y);
        rvh[3] = __builtin_amdgcn_cvt_pkrtz(R1.z, R1.w);
        rvh[4] = __builtin_amdgcn_cvt_pkrtz(R2.x, R2.y);
        rvh[5] = __builtin_amdgcn_cvt_pkrtz(R2.z, R2.w);
        rvh[6] = __builtin_amdgcn_cvt_pkrtz(R3.x, R3.y);
        rvh[7] = __builtin_amdgcn_cvt_pkrtz(R3.z, R3.w);

        // partial_j over own group's 16 cells (own-wave LDS, no barrier)
        const v4f* hp = (const v4f*)(hrow + cellbase);
        v4f h0 = hp[0], h1 = hp[1], h2v = hp[2], h3 = hp[3];
        v2f pacc = v2f{h0.x, h0.y} * Uv2[0] + v2f{h0.z, h0.w} * Uv2[1]
                 + v2f{h1.x, h1.y} * Uv2[2] + v2f{h1.z, h1.w} * Uv2[3]
                 + v2f{h2v.x, h2v.y} * Uv2[4] + v2f{h2v.z, h2v.w} * Uv2[5]
                 + v2f{h3.x, h3.y} * Uv2[6] + v2f{h3.z, h3.w} * Uv2[7];
        float p = pacc.x + pacc.y;
        p += __shfl_xor(p, 16, 64);
        p += __shfl_xor(p, 32, 64);
        if (l < 16) rws[par * 32 + wv * 16 + l] = p;

        // rv-half of the gates while the write drains / other wave catches up
        float a0 = 0.f, a1 = 0.f, a2 = 0.f, a3 = 0.f;
#pragma unroll
        for (int jj = 0; jj < 8; ++jj) {
            a0 = __builtin_amdgcn_fdot2(rvh[jj], VIh[0][jj], a0, false);
            a1 = __builtin_amdgcn_fdot2(rvh[jj], VIh[1][jj], a1, false);
            a2 = __builtin_amdgcn_fdot2(rvh[jj], VIh[2][jj], a2, false);
            a3 = __builtin_amdgcn_fdot2(rvh[jj], VIh[3][jj], a3, false);
        }

        asm volatile("s_waitcnt lgkmcnt(0)" ::: "memory");
        __builtin_amdgcn_s_barrier();
        asm volatile("" ::: "memory");   // fence LDS reads below the barrier,
                                         // but let reg-only FMAs fill the shadow

        // rh = wave0 partial + wave1 partial (broadcast reads) -> f16 pack
        const v4f* pp = (const v4f*)(rws + par * 32);
        v4f q0 = pp[0], q1 = pp[1], q2 = pp[2], q3 = pp[3];
        v4f q4 = pp[4], q5 = pp[5], q6 = pp[6], q7 = pp[7];
        v4f r0 = q0 + q4, r1 = q1 + q5, r2 = q2 + q6, r3 = q3 + q7;
        h2 rhh[8];
        rhh[0] = __builtin_amdgcn_cvt_pkrtz(r0.x, r0.y);
        rhh[1] = __builtin_amdgcn_cvt_pkrtz(r0.z, r0.w);
        rhh[2] = __builtin_amdgcn_cvt_pkrtz(r1.x, r1.y);
        rhh[3] = __builtin_amdgcn_cvt_pkrtz(r1.z, r1.w);
        rhh[4] = __builtin_amdgcn_cvt_pkrtz(r2.x, r2.y);
        rhh[5] = __builtin_amdgcn_cvt_pkrtz(r2.z, r2.w);
        rhh[6] = __builtin_amdgcn_cvt_pkrtz(r3.x, r3.y);
        rhh[7] = __builtin_amdgcn_cvt_pkrtz(r3.z, r3.w);
#pragma unroll
        for (int jj = 0; jj < 8; ++jj) {
            a0 = __builtin_amdgcn_fdot2(rhh[jj], VHh[0][jj], a0, false);
            a1 = __builtin_amdgcn_fdot2(rhh[jj], VHh[1][jj], a1, false);
            a2 = __builtin_amdgcn_fdot2(rhh[jj], VHh[2][jj], a2, false);
            a3 = __builtin_amdgcn_fdot2(rhh[jj], VHh[3][jj], a3, false);
        }
        const float us = 9.765625e-04f;  // 2^-10 unscale
        float g0 = fmaf(a0, us, bsum[0]);
        float g1 = fmaf(a1, us, bsum[1]);
        float g2 = fmaf(a2, us, bsum[2]);
        float g3 = fmaf(a3, us, bsum[3]);

        float cond = fmaxf(fmaxf(fabsf(g0), fabsf(g1)),
                           fmaxf(fmaxf(fabsf(g2), fabsf(g3)), fabsf(c)));
        float hn;
        if (__builtin_expect(__any(cond > 0.07f), 0)) {
            float si = sig_fast(g0), sf = sig_fast(g1);
            float tc = tanh_fast(g2), so = sig_fast(g3);
            c = sf * c + si * tc;
            hn = so * tanh_fast(c);
        } else {
            float si = sig_p(g0), sf = sig_p(g1);
            float tc = tanh_p(g2), so = sig_p(g3);
            c = sf * c + si * tc;         // |c| <= 0.14 by construction
            hn = so * tanh_p(c);
        }

        hrow[t] = hn;                // own-wave, in-order vs next step's read
        hsb[(size_t)s * 128] = hn;   // coalesced, never drained at raw barrier
    }
}

// ---------- kernel 3: last-query attention + head, 1 block/batch ----------
__global__ __launch_bounds__(256) void attn_head_kernel(
    const float* __restrict__ hs,
    const float* __restrict__ Wq, const float* __restrict__ bq,
    const float* __restrict__ Wk,
    const float* __restrict__ Wv, const float* __restrict__ bv,
    const float* __restrict__ Wo, const float* __restrict__ bo,
    const float* __restrict__ Wfc, const float* __restrict__ bfc,
    float* __restrict__ out)
{
    const int b = blockIdx.x;
    const int t = threadIdx.x;
    const float* hb = hs + (size_t)b * (SS * 128);

    __shared__ float hlast[128];
    __shared__ float qv[128];
    __shared__ float wqt[2][128];
    __shared__ float sc[2][1024];
    __shared__ float red[8];
    __shared__ float hbarw[2][128];
    __shared__ float att[128];
    __shared__ float yv[128];

    if (t < 128) hlast[t] = hb[(size_t)1023 * 128 + t];
    __syncthreads();
    if (t < 128) {
        float acc = bq[t];
        for (int c = 0; c < 128; ++c) acc += hlast[c] * Wq[c * 128 + t];
        qv[t] = acc;
    }
    __syncthreads();
    {
        int h = t >> 7, c0 = t & 127;
        float acc = 0.f;
        for (int d = 0; d < 64; ++d) acc += Wk[c0 * 128 + h * 64 + d] * qv[h * 64 + d];
        wqt[h][c0] = acc;
    }
    __syncthreads();
    for (int rr = 0; rr < 4; ++rr) {
        int row = (rr << 8) + t;
        const float4* hp = (const float4*)(hb + (size_t)row * 128);
        float a0 = 0.f, a1 = 0.f;
#pragma unroll 8
        for (int cq = 0; cq < 32; ++cq) {
            float4 hv = hp[cq];
            int cb = cq * 4;
            a0 += hv.x * wqt[0][cb] + hv.y * wqt[0][cb + 1] + hv.z * wqt[0][cb + 2] + hv.w * wqt[0][cb + 3];
            a1 += hv.x * wqt[1][cb] + hv.y * wqt[1][cb + 1] + hv.z * wqt[1][cb + 2] + hv.w * wqt[1][cb + 3];
        }
        sc[0][row] = a0 * 0.125f;
        sc[1][row] = a1 * 0.125f;
    }
    __syncthreads();
    for (int h = 0; h < 2; ++h) {
        float lm = -3.4e38f;
        for (int i = t; i < 1024; i += 256) lm = fmaxf(lm, sc[h][i]);
        for (int off = 1; off < 64; off <<= 1) lm = fmaxf(lm, __shfl_xor(lm, off, 64));
        if ((t & 63) == 0) red[t >> 6] = lm;
        __syncthreads();
        float m = fmaxf(fmaxf(red[0], red[1]), fmaxf(red[2], red[3]));
        float ls = 0.f;
        for (int i = t; i < 1024; i += 256) {
            float e = __expf(sc[h][i] - m);
            sc[h][i] = e;
            ls += e;
        }
        for (int off = 1; off < 64; off <<= 1) ls += __shfl_xor(ls, off, 64);
        if ((t & 63) == 0) red[4 + (t >> 6)] = ls;
        __syncthreads();
        float invL = __builtin_amdgcn_rcpf((red[4] + red[5]) + (red[6] + red[7]));
        for (int i = t; i < 1024; i += 256) sc[h][i] *= invL;
        __syncthreads();
    }
    {
        int h = t >> 7, c0 = t & 127;
        float a0 = 0.f, a1 = 0.f, a2 = 0.f, a3 = 0.f;
        for (int row = 0; row < 1024; row += 4) {
            a0 += sc[h][row]     * hb[(size_t)(row)     * 128 + c0];
            a1 += sc[h][row + 1] * hb[(size_t)(row + 1) * 128 + c0];
            a2 += sc[h][row + 2] * hb[(size_t)(row + 2) * 128 + c0];
            a3 += sc[h][row + 3] * hb[(size_t)(row + 3) * 128 + c0];
        }
        hbarw[h][c0] = (a0 + a1) + (a2 + a3);
    }
    __syncthreads();
    if (t < 128) {
        int h = t >> 6;
        float acc = bv[t];
        for (int c = 0; c < 128; ++c) acc += hbarw[h][c] * Wv[c * 128 + t];
        att[t] = acc;
    }
    __syncthreads();
    if (t < 128) {
        float acc = bo[t];
        for (int c = 0; c < 128; ++c) acc += att[c] * Wo[c * 128 + t];
        yv[t] = acc;
    }
    __syncthreads();
    if (t < 18) {
        float acc = bfc[t];
        for (int c = 0; c < 128; ++c) acc += yv[c] * Wfc[c * 18 + t];
        out[b * 18 + t] = acc;
    }
}

extern "C" void kernel_launch(void* const* d_in, const int* in_sizes, int n_in,
                              void* d_out, int out_size, void* d_ws, size_t ws_size,
                              hipStream_t stream) {
    const float* x    = (const float*)d_in[0];
    const float* w1d  = (const float*)d_in[1];
    const float* b1d  = (const float*)d_in[2];
    const float* w1p  = (const float*)d_in[3];
    const float* b1p  = (const float*)d_in[4];
    const float* w2d  = (const float*)d_in[5];
    const float* b2d  = (const float*)d_in[6];
    const float* w2p  = (const float*)d_in[7];
    const float* b2p  = (const float*)d_in[8];
    const float* w3d  = (const float*)d_in[9];
    const float* b3d  = (const float*)d_in[10];
    const float* w3p  = (const float*)d_in[11];
    const float* b3p  = (const float*)d_in[12];
    const float* Ui   = (const float*)d_in[13];
    const float* Vi   = (const float*)d_in[14];
    const float* Uh   = (const float*)d_in[15];
    const float* Vh   = (const float*)d_in[16];
    const float* bi   = (const float*)d_in[17];
    const float* bh   = (const float*)d_in[18];
    const float* Wq   = (const float*)d_in[19];
    const float* bq   = (const float*)d_in[20];
    const float* Wk   = (const float*)d_in[21];
    // d_in[22] = bk: cancels in softmax (constant shift per (b,h))
    const float* Wv   = (const float*)d_in[23];
    const float* bv   = (const float*)d_in[24];
    const float* Wo   = (const float*)d_in[25];
    const float* bo   = (const float*)d_in[26];
    const float* Wfc  = (const float*)d_in[27];
    const float* bfc  = (const float*)d_in[28];

    float* ri = (float*)d_ws;                       // B*S*16 floats (2 MB, x1024-scaled)
    float* hs = ri + (size_t)BB * SS * 16;          // B*S*128 floats (16 MB)

    conv_ri_kernel<<<dim3(512), dim3(256), 0, stream>>>(
        x, w1d, b1d, w1p, b1p, w2d, b2d, w2p, b2p, w3d, b3d, w3p, b3p, Ui, ri);
    // dynamic LDS: 16384 (rlds) + 128 (hrow) + 64 (rws) floats = 66304 B
    lstm_scan_kernel<<<dim3(32), dim3(128), 66304, stream>>>(
        ri, Uh, Vi, Vh, bi, bh, hs);
    attn_head_kernel<<<dim3(32), dim3(256), 0, stream>>>(
        hs, Wq, bq, Wk, Wv, bv, Wo, bo, Wfc, bfc, (float*)d_out);
}

// Round 8
// 576.836 us; speedup vs baseline: 1.9147x; 1.0642x over previous
//
#include <hip/hip_runtime.h>

#define BB 32
#define SS 1024
#define CINN 16

typedef float v2f __attribute__((ext_vector_type(2)));
typedef float v4f __attribute__((ext_vector_type(4)));
typedef __fp16 h2 __attribute__((ext_vector_type(2)));

// ---------- exact-path activations (any argument) ----------
__device__ __forceinline__ float tanh_fast(float x) {
    float x2 = x * x;
    float p = x * (1.f + x2 * (-0.33333334f + x2 * (0.13333333f - x2 * 0.05396825f)));
    float e = __expf(2.f * x);
    float q = 1.f - 2.f * __builtin_amdgcn_rcpf(1.f + e);
    return (fabsf(x) > 0.25f) ? q : p;
}
__device__ __forceinline__ float sig_fast(float x) {
    return 0.5f + 0.5f * tanh_fast(0.5f * x);
}
// ---------- tiny-argument packed polys (|x| <= 0.07 gates, |c| <= 0.15) ----------
__device__ __forceinline__ v2f tanh_p2(v2f x) {
    v2f x2 = x * x;
    return x * (1.f + x2 * (-0.33333334f + x2 * 0.13333333f));
}
__device__ __forceinline__ v2f sig_p2(v2f x) {
    v2f x2 = x * x;
    return 0.5f + x * (0.25f + x2 * (-0.020833334f + x2 * 0.0020833334f));
}

// ---------- kernel 1: fused 3x dsconv + gx1024 = ((z3@Ui)@Vi + bi + bh)*1024 (f16 pairs) ----------
__global__ __launch_bounds__(256) void conv_gx_kernel(
    const float* __restrict__ x,
    const float* __restrict__ w1d, const float* __restrict__ b1d,
    const float* __restrict__ w1p, const float* __restrict__ b1p,
    const float* __restrict__ w2d, const float* __restrict__ b2d,
    const float* __restrict__ w2p, const float* __restrict__ b2p,
    const float* __restrict__ w3d, const float* __restrict__ b3d,
    const float* __restrict__ w3p, const float* __restrict__ b3p,
    const float* __restrict__ Ui, const float* __restrict__ Vi,
    const float* __restrict__ bi, const float* __restrict__ bh,
    unsigned int* __restrict__ gxh)
{
    const int b = blockIdx.x >> 4;
    const int tile = blockIdx.x & 15;
    const int base = tile * 64;
    const int t = threadIdx.x;

    __shared__ float lds[12576];
    float* xs  = lds;          // [70][16]
    float* y1s = lds + 1120;   // [68][16]
    float* z1s = lds + 2208;   // [68][32]
    float* y2s = lds;          // [66][32]
    float* z2s = lds + 4384;   // [66][64]
    float* y3s = lds;          // [64][64]
    float* z3s = lds + 4384;   // [64][128]
    float* ri_t = lds;         // [64][16]  (overlays xs/y1s area, dead by P7)

    for (int idx = t; idx < 70 * 16; idx += 256) {
        int p = idx >> 4, c = idx & 15;
        int s = base - 3 + p;
        xs[idx] = (s >= 0 && s < SS) ? x[((size_t)b * SS + s) * CINN + c] : 0.f;
    }
    __syncthreads();
    for (int idx = t; idx < 68 * 16; idx += 256) {
        int p = idx >> 4, c = idx & 15;
        float acc = b1d[c];
#pragma unroll
        for (int k = 0; k < 3; ++k) acc += xs[(p + k) * 16 + c] * w1d[c * 3 + k];
        y1s[idx] = acc;
    }
    __syncthreads();
    for (int idx = t; idx < 68 * 32; idx += 256) {
        int p = idx >> 5, o = idx & 31;
        int pos = base - 2 + p;
        float acc = b1p[o];
#pragma unroll
        for (int c = 0; c < 16; ++c) acc += y1s[p * 16 + c] * w1p[o * 16 + c];
        z1s[idx] = (pos >= 0 && pos < SS) ? acc : 0.f;
    }
    __syncthreads();
    for (int idx = t; idx < 66 * 32; idx += 256) {
        int p = idx >> 5, c = idx & 31;
        float acc = b2d[c];
#pragma unroll
        for (int k = 0; k < 3; ++k) acc += z1s[(p + k) * 32 + c] * w2d[c * 3 + k];
        y2s[idx] = acc;
    }
    __syncthreads();
    for (int idx = t; idx < 66 * 64; idx += 256) {
        int p = idx >> 6, o = idx & 63;
        int pos = base - 1 + p;
        float acc = b2p[o];
        for (int c = 0; c < 32; ++c) acc += y2s[p * 32 + c] * w2p[o * 32 + c];
        z2s[idx] = (pos >= 0 && pos < SS) ? acc : 0.f;
    }
    __syncthreads();
    for (int idx = t; idx < 64 * 64; idx += 256) {
        int p = idx >> 6, c = idx & 63;
        float acc = b3d[c];
#pragma unroll
        for (int k = 0; k < 3; ++k) acc += z2s[(p + k) * 64 + c] * w3d[c * 3 + k];
        y3s[idx] = acc;
    }
    __syncthreads();
    for (int idx = t; idx < 64 * 128; idx += 256) {
        int p = idx >> 7, o = idx & 127;
        float acc = b3p[o];
        for (int c = 0; c < 64; ++c) acc += y3s[p * 64 + c] * w3p[o * 64 + c];
        z3s[idx] = acc;
    }
    __syncthreads();
    // P7: ri tile (64 x 16) -> LDS
    for (int idx = t; idx < 64 * 16; idx += 256) {
        int p = idx >> 4, jj = idx & 15;
        float acc = 0.f;
        for (int o = 0; o < 128; ++o) acc += z3s[p * 128 + o] * Ui[o * 16 + jj];
        ri_t[idx] = acc;
    }
    __syncthreads();
    // P8: gx1024[b][s][gate][l] = f16pair( 1024*(dot(ri,Vi[:,ga]) + bias[ga]),
    //                                      1024*(dot(ri,Vi[:,gb]) + bias[gb]) )
    {
        const int l = t & 63, gate = t >> 6;
        const int ga = gate * 128 + l, gb = ga + 64;
        v2f viv[16];
#pragma unroll
        for (int jj = 0; jj < 16; ++jj)
            viv[jj] = v2f{ Vi[jj * 512 + ga] * 1024.f, Vi[jj * 512 + gb] * 1024.f };
        v2f bias2 = v2f{ (bi[ga] + bh[ga]) * 1024.f, (bi[gb] + bh[gb]) * 1024.f };
        unsigned int* og = gxh + ((size_t)b * SS + base) * 256 + gate * 64 + l;
        for (int p = 0; p < 64; ++p) {
            const float* rr = ri_t + p * 16;
            v2f acc = bias2;
#pragma unroll
            for (int jj = 0; jj < 16; ++jj) acc += rr[jj] * viv[jj];
            h2 ph = __builtin_amdgcn_cvt_pkrtz(acc.x, acc.y);
            og[(size_t)p * 256] = __builtin_bit_cast(unsigned int, ph);
        }
    }
}

// ---------- kernel 2: low-rank LSTM scan — 1 wave = 1 batch, 2 cells/lane ----------
// No barriers (single-wave block; same-wave DS ops are pipe-ordered).
// CORRECT r-reduce: lane (grp=l>>4, j=l&15) reads 32 h cells
// [16g,16g+16) u [64+16g,+16) from LDS, partial = sum h*Uh[cell][j] (x1024);
// permlane32_swap folds groups {g, g^2}; lanes 0-31 stage the two halves in
// LDS; every lane reads both halves and adds -> full 128-cell r_j, all j.
__global__ __launch_bounds__(64, 1) void lstm_scan_kernel(
    const unsigned int* __restrict__ gxh,
    const float* __restrict__ Uh,
    const float* __restrict__ Vh,
    float* __restrict__ hs)
{
    const int b = blockIdx.x;
    const int l = threadIdx.x;
    const int j = l & 15;
    const int grp = l >> 4;

    __shared__ float hbuf[128];
    __shared__ float rexf[32];

    // Uh rows (x1024) for this lane's 32-cell coverage, column j: 32 VGPRs
    v2f UvA[8], UvB[8];
#pragma unroll
    for (int i = 0; i < 8; ++i) {
        UvA[i] = v2f{ Uh[(16 * grp + 2 * i) * 16 + j] * 1024.f,
                      Uh[(16 * grp + 2 * i + 1) * 16 + j] * 1024.f };
        UvB[i] = v2f{ Uh[(64 + 16 * grp + 2 * i) * 16 + j] * 1024.f,
                      Uh[(64 + 16 * grp + 2 * i + 1) * 16 + j] * 1024.f };
    }

    // V_h packed f16, per-lane output columns for cells (l, l+64): 64 VGPRs
    h2 VHh[2][4][8];
#pragma unroll
    for (int cell = 0; cell < 2; ++cell)
#pragma unroll
        for (int g = 0; g < 4; ++g)
#pragma unroll
            for (int jj = 0; jj < 8; ++jj) {
                int col = g * 128 + l + 64 * cell;
                VHh[cell][g][jj] = __builtin_amdgcn_cvt_pkrtz(
                    Vh[(2 * jj) * 512 + col], Vh[(2 * jj + 1) * 512 + col]);
            }

    const unsigned int* gxb = gxh + (size_t)b * SS * 256 + l;
    float* hsb = hs + (size_t)b * SS * 128;

    hbuf[l] = 0.f;            // h_{-1} = 0 (same-wave DS order, no barrier)
    hbuf[l + 64] = 0.f;

    unsigned int gA[4], gB[4];
#pragma unroll
    for (int g = 0; g < 4; ++g) gA[g] = gxb[g * 64];  // s = 0

    v2f hv = {0.f, 0.f}, cv = {0.f, 0.f};
    const float us = 9.765625e-04f;                   // 2^-10 shared unscale

    const v4f* hpA = (const v4f*)(hbuf + 16 * grp);
    const v4f* hpB = (const v4f*)(hbuf + 64 + 16 * grp);
    const v4f* rp  = (const v4f*)rexf;

#define LSTM_STEP(S, CUR, NXT)                                                     \
    {                                                                              \
        const int s_ = (S);                                                        \
        const int sp_ = (s_ + 1 < SS) ? s_ + 1 : SS - 1;                           \
        const unsigned int* gp_ = gxb + (size_t)sp_ * 256;                         \
        _Pragma("unroll")                                                          \
        for (int g = 0; g < 4; ++g) NXT[g] = gp_[g * 64];                          \
        /* 32-cell partial for column j (h_{s-1} from LDS) */                      \
        v4f ha0_ = hpA[0], ha1_ = hpA[1], ha2_ = hpA[2], ha3_ = hpA[3];            \
        v4f hb0_ = hpB[0], hb1_ = hpB[1], hb2_ = hpB[2], hb3_ = hpB[3];            \
        v2f acc_ = v2f{ha0_.x, ha0_.y} * UvA[0] + v2f{ha0_.z, ha0_.w} * UvA[1]     \
                 + v2f{ha1_.x, ha1_.y} * UvA[2] + v2f{ha1_.z, ha1_.w} * UvA[3]     \
                 + v2f{ha2_.x, ha2_.y} * UvA[4] + v2f{ha2_.z, ha2_.w} * UvA[5]     \
                 + v2f{ha3_.x, ha3_.y} * UvA[6] + v2f{ha3_.z, ha3_.w} * UvA[7]     \
                 + v2f{hb0_.x, hb0_.y} * UvB[0] + v2f{hb0_.z, hb0_.w} * UvB[1]     \
                 + v2f{hb1_.x, hb1_.y} * UvB[2] + v2f{hb1_.z, hb1_.w} * UvB[3]     \
                 + v2f{hb2_.x, hb2_.y} * UvB[4] + v2f{hb2_.z, hb2_.w} * UvB[5]     \
                 + v2f{hb3_.x, hb3_.y} * UvB[6] + v2f{hb3_.z, hb3_.w} * UvB[7];    \
        float p_ = acc_.x + acc_.y;                                                \
        float t1_;                                                                 \
        asm volatile("v_mov_b32 %0, %1\n\t"                                        \
                     "v_permlane32_swap_b32 %1, %0"                                \
                     : "=&v"(t1_), "+v"(p_));                                      \
        p_ += t1_;   /* groups {g, g^2} combined; lanes 0-31 hold both halves */   \
        if (l < 32) rexf[l] = p_;                                                  \
        v4f rA0_ = rp[0], rA1_ = rp[1], rA2_ = rp[2], rA3_ = rp[3];                \
        v4f rB0_ = rp[4], rB1_ = rp[5], rB2_ = rp[6], rB3_ = rp[7];                \
        v4f r0_ = rA0_ + rB0_, r1_ = rA1_ + rB1_;                                  \
        v4f r2_ = rA2_ + rB2_, r3_ = rA3_ + rB3_;                                  \
        h2 rhh_[8];                                                                \
        rhh_[0] = __builtin_amdgcn_cvt_pkrtz(r0_.x, r0_.y);                        \
        rhh_[1] = __builtin_amdgcn_cvt_pkrtz(r0_.z, r0_.w);                        \
        rhh_[2] = __builtin_amdgcn_cvt_pkrtz(r1_.x, r1_.y);                        \
        rhh_[3] = __builtin_amdgcn_cvt_pkrtz(r1_.z, r1_.w);                        \
        rhh_[4] = __builtin_amdgcn_cvt_pkrtz(r2_.x, r2_.y);                        \
        rhh_[5] = __builtin_amdgcn_cvt_pkrtz(r2_.z, r2_.w);                        \
        rhh_[6] = __builtin_amdgcn_cvt_pkrtz(r3_.x, r3_.y);                        \
        rhh_[7] = __builtin_amdgcn_cvt_pkrtz(r3_.z, r3_.w);                        \
        float aA_[4] = {0.f, 0.f, 0.f, 0.f}, aB_[4] = {0.f, 0.f, 0.f, 0.f};        \
        _Pragma("unroll")                                                          \
        for (int jj = 0; jj < 8; ++jj) {                                           \
            _Pragma("unroll")                                                      \
            for (int g = 0; g < 4; ++g) {                                          \
                aA_[g] = __builtin_amdgcn_fdot2(rhh_[jj], VHh[0][g][jj], aA_[g], false); \
                aB_[g] = __builtin_amdgcn_fdot2(rhh_[jj], VHh[1][g][jj], aB_[g], false); \
            }                                                                      \
        }                                                                          \
        v2f gt_[4];                                                                \
        _Pragma("unroll")                                                          \
        for (int g = 0; g < 4; ++g) {                                              \
            h2 gh_ = __builtin_bit_cast(h2, CUR[g]);                               \
            gt_[g] = v2f{ (aA_[g] + (float)gh_.x) * us,                            \
                          (aB_[g] + (float)gh_.y) * us };                          \
        }                                                                          \
        v2f gi_ = gt_[0], gf_ = gt_[1], gc_ = gt_[2], go_ = gt_[3];                \
        float cond_ = fmaxf(                                                       \
            fmaxf(fmaxf(fabsf(gi_.x), fabsf(gi_.y)),                               \
                  fmaxf(fabsf(gf_.x), fabsf(gf_.y))),                              \
            fmaxf(fmaxf(fabsf(gc_.x), fabsf(gc_.y)),                               \
                  fmaxf(fmaxf(fabsf(go_.x), fabsf(go_.y)),                         \
                        fmaxf(fabsf(cv.x), fabsf(cv.y)))));                        \
        if (__builtin_expect(__any(cond_ > 0.07f), 0)) {                           \
            v2f si_ = { sig_fast(gi_.x), sig_fast(gi_.y) };                        \
            v2f sf_ = { sig_fast(gf_.x), sig_fast(gf_.y) };                        \
            v2f tc_ = { tanh_fast(gc_.x), tanh_fast(gc_.y) };                      \
            v2f so_ = { sig_fast(go_.x), sig_fast(go_.y) };                        \
            cv = sf_ * cv + si_ * tc_;                                             \
            hv = so_ * v2f{ tanh_fast(cv.x), tanh_fast(cv.y) };                    \
        } else {                                                                   \
            v2f si_ = sig_p2(gi_), sf_ = sig_p2(gf_);                              \
            v2f tc_ = tanh_p2(gc_), so_ = sig_p2(go_);                             \
            cv = sf_ * cv + si_ * tc_;                                             \
            hv = so_ * tanh_p2(cv);                                                \
        }                                                                          \
        hbuf[l] = hv.x;        /* same-wave DS order protects next step's read */  \
        hbuf[l + 64] = hv.y;                                                       \
        float* hh_ = hsb + (size_t)s_ * 128;                                       \
        hh_[l] = hv.x;                                                             \
        hh_[l + 64] = hv.y;                                                        \
    }

    for (int s = 0; s < SS; s += 2) {
        LSTM_STEP(s, gA, gB);
        LSTM_STEP(s + 1, gB, gA);
    }
#undef LSTM_STEP
}

// ---------- kernel 3: last-query attention + head, 1 block/batch ----------
__global__ __launch_bounds__(256) void attn_head_kernel(
    const float* __restrict__ hs,
    const float* __restrict__ Wq, const float* __restrict__ bq,
    const float* __restrict__ Wk,
    const float* __restrict__ Wv, const float* __restrict__ bv,
    const float* __restrict__ Wo, const float* __restrict__ bo,
    const float* __restrict__ Wfc, const float* __restrict__ bfc,
    float* __restrict__ out)
{
    const int b = blockIdx.x;
    const int t = threadIdx.x;
    const float* hb = hs + (size_t)b * (SS * 128);

    __shared__ float hlast[128];
    __shared__ float qv[128];
    __shared__ float wqt[2][128];
    __shared__ float sc[2][1024];
    __shared__ float red[8];
    __shared__ float hbarw[2][128];
    __shared__ float att[128];
    __shared__ float yv[128];

    if (t < 128) hlast[t] = hb[(size_t)1023 * 128 + t];
    __syncthreads();
    if (t < 128) {
        float acc = bq[t];
        for (int c = 0; c < 128; ++c) acc += hlast[c] * Wq[c * 128 + t];
        qv[t] = acc;
    }
    __syncthreads();
    {
        int h = t >> 7, c0 = t & 127;
        float acc = 0.f;
        for (int d = 0; d < 64; ++d) acc += Wk[c0 * 128 + h * 64 + d] * qv[h * 64 + d];
        wqt[h][c0] = acc;
    }
    __syncthreads();
    for (int rr = 0; rr < 4; ++rr) {
        int row = (rr << 8) + t;
        const float4* hp = (const float4*)(hb + (size_t)row * 128);
        float a0 = 0.f, a1 = 0.f;
#pragma unroll 8
        for (int cq = 0; cq < 32; ++cq) {
            float4 hv = hp[cq];
            int cb = cq * 4;
            a0 += hv.x * wqt[0][cb] + hv.y * wqt[0][cb + 1] + hv.z * wqt[0][cb + 2] + hv.w * wqt[0][cb + 3];
            a1 += hv.x * wqt[1][cb] + hv.y * wqt[1][cb + 1] + hv.z * wqt[1][cb + 2] + hv.w * wqt[1][cb + 3];
        }
        sc[0][row] = a0 * 0.125f;
        sc[1][row] = a1 * 0.125f;
    }
    __syncthreads();
    for (int h = 0; h < 2; ++h) {
        float lm = -3.4e38f;
        for (int i = t; i < 1024; i += 256) lm = fmaxf(lm, sc[h][i]);
        for (int off = 1; off < 64; off <<= 1) lm = fmaxf(lm, __shfl_xor(lm, off, 64));
        if ((t & 63) == 0) red[t >> 6] = lm;
        __syncthreads();
        float m = fmaxf(fmaxf(red[0], red[1]), fmaxf(red[2], red[3]));
        float ls = 0.f;
        for (int i = t; i < 1024; i += 256) {
            float e = __expf(sc[h][i] - m);
            sc[h][i] = e;
            ls += e;
        }
        for (int off = 1; off < 64; off <<= 1) ls += __shfl_xor(ls, off, 64);
        if ((t & 63) == 0) red[4 + (t >> 6)] = ls;
        __syncthreads();
        float invL = __builtin_amdgcn_rcpf((red[4] + red[5]) + (red[6] + red[7]));
        for (int i = t; i < 1024; i += 256) sc[h][i] *= invL;
        __syncthreads();
    }
    {
        int h = t >> 7, c0 = t & 127;
        float a0 = 0.f, a1 = 0.f, a2 = 0.f, a3 = 0.f;
        for (int row = 0; row < 1024; row += 4) {
            a0 += sc[h][row]     * hb[(size_t)(row)     * 128 + c0];
            a1 += sc[h][row + 1] * hb[(size_t)(row + 1) * 128 + c0];
            a2 += sc[h][row + 2] * hb[(size_t)(row + 2) * 128 + c0];
            a3 += sc[h][row + 3] * hb[(size_t)(row + 3) * 128 + c0];
        }
        hbarw[h][c0] = (a0 + a1) + (a2 + a3);
    }
    __syncthreads();
    if (t < 128) {
        int h = t >> 6;
        float acc = bv[t];
        for (int c = 0; c < 128; ++c) acc += hbarw[h][c] * Wv[c * 128 + t];
        att[t] = acc;
    }
    __syncthreads();
    if (t < 128) {
        float acc = bo[t];
        for (int c = 0; c < 128; ++c) acc += att[c] * Wo[c * 128 + t];
        yv[t] = acc;
    }
    __syncthreads();
    if (t < 18) {
        float acc = bfc[t];
        for (int c = 0; c < 128; ++c) acc += yv[c] * Wfc[c * 18 + t];
        out[b * 18 + t] = acc;
    }
}

extern "C" void kernel_launch(void* const* d_in, const int* in_sizes, int n_in,
                              void* d_out, int out_size, void* d_ws, size_t ws_size,
                              hipStream_t stream) {
    const float* x    = (const float*)d_in[0];
    const float* w1d  = (const float*)d_in[1];
    const float* b1d  = (const float*)d_in[2];
    const float* w1p  = (const float*)d_in[3];
    const float* b1p  = (const float*)d_in[4];
    const float* w2d  = (const float*)d_in[5];
    const float* b2d  = (const float*)d_in[6];
    const float* w2p  = (const float*)d_in[7];
    const float* b2p  = (const float*)d_in[8];
    const float* w3d  = (const float*)d_in[9];
    const float* b3d  = (const float*)d_in[10];
    const float* w3p  = (const float*)d_in[11];
    const float* b3p  = (const float*)d_in[12];
    const float* Ui   = (const float*)d_in[13];
    const float* Vi   = (const float*)d_in[14];
    const float* Uh   = (const float*)d_in[15];
    const float* Vh   = (const float*)d_in[16];
    const float* bi   = (const float*)d_in[17];
    const float* bh   = (const float*)d_in[18];
    const float* Wq   = (const float*)d_in[19];
    const float* bq   = (const float*)d_in[20];
    const float* Wk   = (const float*)d_in[21];
    // d_in[22] = bk: cancels in softmax (constant shift per (b,h))
    const float* Wv   = (const float*)d_in[23];
    const float* bv   = (const float*)d_in[24];
    const float* Wo   = (const float*)d_in[25];
    const float* bo   = (const float*)d_in[26];
    const float* Wfc  = (const float*)d_in[27];
    const float* bfc  = (const float*)d_in[28];

    unsigned int* gxh = (unsigned int*)d_ws;                  // B*S*256 u32 = 32 MB (f16 gate pairs, x1024)
    float* hs = (float*)(gxh + (size_t)BB * SS * 256);        // B*S*128 f32 = 16 MB

    conv_gx_kernel<<<dim3(512), dim3(256), 0, stream>>>(
        x, w1d, b1d, w1p, b1p, w2d, b2d, w2p, b2p, w3d, b3d, w3p, b3p,
        Ui, Vi, bi, bh, gxh);
    lstm_scan_kernel<<<dim3(32), dim3(64), 0, stream>>>(
        gxh, Uh, Vh, hs);
    attn_head_kernel<<<dim3(32), dim3(256), 0, stream>>>(
        hs, Wq, bq, Wk, Wv, bv, Wo, bo, Wfc, bfc, (float*)d_out);
}